// Round 15
// baseline (17.296 us; speedup 1.0000x reference)
//
#include <hip/hip_runtime.h>

#define RPB 32              // residues per block (8 lanes per residue)
#define FRS 14              // LDS floats per frame: rows 0..2 (12) + 2 pad
#define RSS (9*FRS)         // 126 floats per residue
#define PS  68              // P-exchange: 4 mats x16 + 4 pad (16B-aligned: 272B)

// ---------- helpers ----------

__device__ __forceinline__ float rsqz(float d) { return rsqrtf(fmaxf(d, 1e-24f)); }

__device__ __forceinline__ void angNorm(float x, float y, float& c, float& s) {
    float inv = rsqz(x*x + y*y);
    c = x * inv; s = y * inv;
}

// row-vector times 4x4 matrix; B points at 16 floats (row-major), LDS or global
__device__ __forceinline__ float4 rowMat(const float4 f, const float* B) {
    float4 b0 = *reinterpret_cast<const float4*>(B);
    float4 b1 = *reinterpret_cast<const float4*>(B + 4);
    float4 b2 = *reinterpret_cast<const float4*>(B + 8);
    float4 b3 = *reinterpret_cast<const float4*>(B + 12);
    float4 o;
    o.x = f.x*b0.x + f.y*b1.x + f.z*b2.x + f.w*b3.x;
    o.y = f.x*b0.y + f.y*b1.y + f.z*b2.y + f.w*b3.y;
    o.z = f.x*b0.z + f.y*b1.z + f.z*b2.z + f.w*b3.z;
    o.w = f.x*b0.w + f.y*b1.w + f.z*b2.w + f.w*b3.w;
    return o;
}

__device__ __forceinline__ void rotXrow(float4& v, float c, float s) {
    float v1 = v.y, v2 = v.z;
    v.y = c*v1 + s*v2;
    v.z = c*v2 - s*v1;
}

__device__ __forceinline__ void rotZrow(float4& v, float c, float s) {
    float v0 = v.x, v1 = v.y;
    v.x = c*v0 + s*v1;
    v.y = c*v1 - s*v0;
}

__device__ __forceinline__ float4 applyG(const float4 f, const float G[3][3]) {
    float4 o;
    o.x = f.x*G[0][0] + f.y*G[1][0] + f.z*G[2][0];
    o.y = f.x*G[0][1] + f.y*G[1][1] + f.z*G[2][1];
    o.z = f.x*G[0][2] + f.y*G[1][2] + f.z*G[2][2];
    o.w = f.w;
    return o;
}

__device__ __forceinline__ void rotAxis3(float G[3][3], float c, float s,
                                         float u0, float u1, float u2) {
    float omc = 1.0f - c;
    G[0][0] = c + u0*u0*omc;    G[0][1] = u0*u1*omc - u2*s; G[0][2] = u0*u2*omc + u1*s;
    G[1][0] = u0*u1*omc + u2*s; G[1][1] = c + u1*u1*omc;    G[1][2] = u1*u2*omc - u0*s;
    G[2][0] = u0*u2*omc - u1*s; G[2][1] = u1*u2*omc + u0*s; G[2][2] = c + u2*u2*omc;
}

// write one frame row (i<3 only) to LDS as 2x float2 (8B aligned)
__device__ __forceinline__ void ldsRow(float* fl, int frame, int i, const float4 v) {
    if (i < 3) {
        float* d = fl + frame*FRS + i*4;
        *reinterpret_cast<float2*>(d)     = make_float2(v.x, v.y);
        *reinterpret_cast<float2*>(d + 2) = make_float2(v.z, v.w);
    }
}

// ---------------------------- fused kernel ----------------------------
// 256 threads = 4 waves, no barriers. 8 lanes per residue (RPB=32 -> 1024
// blocks -> 4096 waves, 2x the old TLP). Within each 8-lane group:
//  low 4 lanes (u<4): GS -> F0, F1..F3, axes -> F8 (row i = u), LDS+global.
//  high 4 lanes (u>=4): suffix chain P4..P7 rows in base coords (row j=u-4),
//    exchange P via LDS, read F8 rows from LDS (written by low lanes of the
//    SAME wave -> ds program order guarantees visibility, no barrier), then
//    F4..F7 = rowMat(F8row, P_k) -- 4 INDEPENDENT rowMats (chain cut 4x).
// Atom phase: all 64 lanes, 288 atoms per wave.

__global__ __launch_bounds__(256, 4) void fused_kernel(
    const int*   __restrict__ seq,     // (BL)
    const float* __restrict__ xyz,     // (BL,3,3)
    const float* __restrict__ alphas,  // (BL,10,2)
    const int*   __restrict__ bidx,    // (NAA,36)
    const float* __restrict__ RTs,     // (NAA,7,4,4)
    const float* __restrict__ xibf,    // (NAA,36,4)
    float*       __restrict__ out_fr,  // (BL,9,4,4)
    float*       __restrict__ out_xyz, // (BL,36,3)
    int BL)
{
    __shared__ __align__(16) float lds_fr[RPB * RSS];   // 15.8 KB
    __shared__ __align__(16) float lds_P [RPB * PS];    // 8.5 KB
    __shared__ int lds_seq[RPB];

    const int tid  = threadIdx.x;
    const int lane = tid & 63;
    const int wv   = tid >> 6;
    const int u    = lane & 7;            // position in 8-lane group
    const int g    = lane >> 3;           // group (residue) within wave
    const int i    = u & 3;               // row index 0..3 (both roles)
    const bool low = (u < 4);
    const int res  = wv*8 + g;            // residue within block (0..31)
    const int base = blockIdx.x * RPB;
    const int t    = base + res;
    const bool valid = (t < BL);

    float* fl = lds_fr + res * RSS;
    float* pl = lds_P  + res * PS;
    float* fg = out_fr + (size_t)t * 144;

    int s = 0;
    if (valid) s = seq[t];
    const float* rb = RTs + (size_t)s * 112;
    const float* al = alphas + (size_t)t * 20;

    if (valid && low) {
        if (u == 0) lds_seq[res] = s;

        // ---- Gram-Schmidt (redundant across the 4 low lanes) ----
        const float* p = xyz + (size_t)t * 9;
        float N0=p[0], N1=p[1], N2=p[2];
        float A0=p[3], A1=p[4], A2=p[5];
        float C0=p[6], C1=p[7], C2=p[8];
        float v10=C0-A0, v11=C1-A1, v12=C2-A2;
        float v20=N0-A0, v21=N1-A1, v22=N2-A2;
        float i1 = rsqz(v10*v10 + v11*v11 + v12*v12);
        float e10=v10*i1, e11=v11*i1, e12=v12*i1;
        float d  = e10*v20 + e11*v21 + e12*v22;
        float u20=v20-e10*d, u21=v21-e11*d, u22=v22-e12*d;
        float i2 = rsqz(u20*u20 + u21*u21 + u22*u22);
        float e20=u20*i2, e21=u21*i2, e22=u22*i2;
        float e30=e11*e22 - e12*e21;
        float e31=e12*e20 - e10*e22;
        float e32=e10*e21 - e11*e20;

        bool c0 = (i==0), c1 = (i==1), c2 = (i==2);
        float4 f0r;
        f0r.x = c0?e10 : c1?e11 : c2?e12 : 0.f;
        f0r.y = c0?e20 : c1?e21 : c2?e22 : 0.f;
        f0r.z = c0?e30 : c1?e31 : c2?e32 : 0.f;
        f0r.w = c0?A0  : c1?A1  : c2?A2  : 1.f;
        ldsRow(fl, 0, i, f0r);
        *reinterpret_cast<float4*>(fg + i*4) = f0r;

        // ---- angles needed by low path: a0,a1,a2,a7,a8 ----
        float2 A0p = *reinterpret_cast<const float2*>(al + 0);
        float2 A1p = *reinterpret_cast<const float2*>(al + 2);
        float2 A2p = *reinterpret_cast<const float2*>(al + 4);
        float2 A7p = *reinterpret_cast<const float2*>(al + 14);
        float2 A8p = *reinterpret_cast<const float2*>(al + 16);
        float ca0,sa0, ca1,sa1, ca2,sa2, ca7,sa7, ca8,sa8;
        angNorm(A0p.x,A0p.y, ca0,sa0);
        angNorm(A1p.x,A1p.y, ca1,sa1);
        angNorm(A2p.x,A2p.y, ca2,sa2);
        angNorm(A7p.x,A7p.y, ca7,sa7);
        angNorm(A8p.x,A8p.y, ca8,sa8);

        // ---- F1..F3 ----
        float4 rw;
        rw = rowMat(f0r, rb +  0); rotXrow(rw, ca0, sa0);
        ldsRow(fl, 1, i, rw);
        *reinterpret_cast<float4*>(fg + 16 + i*4) = rw;
        rw = rowMat(f0r, rb + 16); rotXrow(rw, ca1, sa1);
        ldsRow(fl, 2, i, rw);
        *reinterpret_cast<float4*>(fg + 32 + i*4) = rw;
        rw = rowMat(f0r, rb + 32); rotXrow(rw, ca2, sa2);
        ldsRow(fl, 3, i, rw);
        *reinterpret_cast<float4*>(fg + 48 + i*4) = rw;

        // ---- CB axes (redundant across low lanes) ----
        const float* bxp = xibf + (size_t)s * 144;
        float4 b0 = reinterpret_cast<const float4*>(bxp)[0];
        float4 b1 = reinterpret_cast<const float4*>(bxp)[1];
        float4 b2 = reinterpret_cast<const float4*>(bxp)[2];
        float4 b4 = reinterpret_cast<const float4*>(bxp)[4];

        float NCr0 = 0.5f*(b2.x + b0.x), NCr1 = 0.5f*(b2.y + b0.y), NCr2 = 0.5f*(b2.z + b0.z);
        float ba0 = b4.x - b1.x, ba1 = b4.y - b1.y, ba2 = b4.z - b1.z;
        float w0 = NCr0 - b1.x, w1 = NCr1 - b1.y, w2 = NCr2 - b1.z;
        float x10 = ba1*w2 - ba2*w1, x11 = ba2*w0 - ba0*w2, x12 = ba0*w1 - ba1*w0;
        float in1 = rsqz(x10*x10 + x11*x11 + x12*x12);
        x10 *= in1; x11 *= in1; x12 *= in1;
        float NCp0 = b2.x - b0.x, NCp1 = b2.y - b0.y, NCp2 = b2.z - b0.z;
        float dp = NCp0*NCr0 + NCp1*NCr1 + NCp2*NCr2;
        float dr = NCr0*NCr0 + NCr1*NCr1 + NCr2*NCr2;
        float sf = dp / dr;
        float g0 = NCp0 - sf*NCr0, g1 = NCp1 - sf*NCr1, g2 = NCp2 - sf*NCr2;
        float x20 = ba1*g2 - ba2*g1, x21 = ba2*g0 - ba0*g2, x22 = ba0*g1 - ba1*g0;
        float in2 = rsqz(x20*x20 + x21*x21 + x22*x22);
        x20 *= in2; x21 *= in2; x22 *= in2;

        float G1[3][3], G2[3][3];
        rotAxis3(G1, ca7, sa7, x10, x11, x12);
        rotAxis3(G2, ca8, sa8, x20, x21, x22);

        // ---- F8 ----
        float4 f8r = applyG(applyG(f0r, G1), G2);
        ldsRow(fl, 8, i, f8r);
        *reinterpret_cast<float4*>(fg + 128 + i*4) = f8r;
    }

    if (valid && !low) {
        // ---- angles needed by high path: a3,a4,a5,a6,a9 ----
        float2 A3p = *reinterpret_cast<const float2*>(al + 6);
        float2 A4p = *reinterpret_cast<const float2*>(al + 8);
        float2 A5p = *reinterpret_cast<const float2*>(al + 10);
        float2 A6p = *reinterpret_cast<const float2*>(al + 12);
        float2 A9p = *reinterpret_cast<const float2*>(al + 18);
        float ca3,sa3, ca4,sa4, ca5,sa5, ca6,sa6, ca9,sa9;
        angNorm(A3p.x,A3p.y, ca3,sa3);
        angNorm(A4p.x,A4p.y, ca4,sa4);
        angNorm(A5p.x,A5p.y, ca5,sa5);
        angNorm(A6p.x,A6p.y, ca6,sa6);
        angNorm(A9p.x,A9p.y, ca9,sa9);

        // ---- suffix chain rows (base coords): P4 = B3@X3@Z9, P5..P7 ----
        float4 p4 = *reinterpret_cast<const float4*>(rb + 48 + i*4);   // row i of B3
        rotXrow(p4, ca3, sa3);
        rotZrow(p4, ca9, sa9);
        float4 p5 = rowMat(p4, rb + 64); rotXrow(p5, ca4, sa4);
        float4 p6 = rowMat(p5, rb + 80); rotXrow(p6, ca5, sa5);
        float4 p7 = rowMat(p6, rb + 96); rotXrow(p7, ca6, sa6);

        // exchange P rows via LDS (full 4x4 each, 16B-aligned)
        *reinterpret_cast<float4*>(pl +  0 + i*4) = p4;
        *reinterpret_cast<float4*>(pl + 16 + i*4) = p5;
        *reinterpret_cast<float4*>(pl + 32 + i*4) = p6;
        *reinterpret_cast<float4*>(pl + 48 + i*4) = p7;

        // ---- read F8 row (written by low lanes of the same wave) ----
        float4 f8row;
        if (i < 3) {
            float2 a2_ = *reinterpret_cast<const float2*>(fl + 8*FRS + i*4);
            float2 b2_ = *reinterpret_cast<const float2*>(fl + 8*FRS + i*4 + 2);
            f8row = make_float4(a2_.x, a2_.y, b2_.x, b2_.y);
        } else {
            f8row = make_float4(0.f, 0.f, 0.f, 1.f);
        }

        // ---- F4..F7: 4 independent rowMats ----
        float4 r;
        r = rowMat(f8row, pl +  0);
        ldsRow(fl, 4, i, r);
        *reinterpret_cast<float4*>(fg +  64 + i*4) = r;
        r = rowMat(f8row, pl + 16);
        ldsRow(fl, 5, i, r);
        *reinterpret_cast<float4*>(fg +  80 + i*4) = r;
        r = rowMat(f8row, pl + 32);
        ldsRow(fl, 6, i, r);
        *reinterpret_cast<float4*>(fg +  96 + i*4) = r;
        r = rowMat(f8row, pl + 48);
        ldsRow(fl, 7, i, r);
        *reinterpret_cast<float4*>(fg + 112 + i*4) = r;
    }

    // ---- atom phase: all lanes, 288 atoms per wave (no barriers) ----
    const int wbase = wv * 8;
#pragma unroll
    for (int k = 0; k < 5; ++k) {
        int c = k*64 + lane;              // 0..319; guard to 288
        if (c < 288) {
            int lres = c / 36;
            int a = c - lres*36;
            int res2 = wbase + lres;
            int tt = base + res2;
            if (tt < BL) {
                int ss  = lds_seq[res2];
                int idx = bidx[ss*36 + a];
                float4 v = *reinterpret_cast<const float4*>(xibf + ((size_t)ss*36 + a)*4);
                const float* fp = lds_fr + res2*RSS + idx*FRS;
                float2 r00 = *reinterpret_cast<const float2*>(fp + 0);
                float2 r01 = *reinterpret_cast<const float2*>(fp + 2);
                float2 r10 = *reinterpret_cast<const float2*>(fp + 4);
                float2 r11 = *reinterpret_cast<const float2*>(fp + 6);
                float2 r20 = *reinterpret_cast<const float2*>(fp + 8);
                float2 r21 = *reinterpret_cast<const float2*>(fp + 10);
                size_t o = ((size_t)(base + wbase)*36 + c)*3;   // dense in c per wave
                out_xyz[o+0] = r00.x*v.x + r00.y*v.y + r01.x*v.z + r01.y*v.w;
                out_xyz[o+1] = r10.x*v.x + r10.y*v.y + r11.x*v.z + r11.y*v.w;
                out_xyz[o+2] = r20.x*v.x + r20.y*v.y + r21.x*v.z + r21.y*v.w;
            }
        }
    }
}

// ---------------------------- launch ----------------------------

extern "C" void kernel_launch(void* const* d_in, const int* in_sizes, int n_in,
                              void* d_out, int out_size, void* d_ws, size_t ws_size,
                              hipStream_t stream) {
    const int*   seq    = (const int*)  d_in[0];
    const float* xyz    = (const float*)d_in[1];
    const float* alphas = (const float*)d_in[2];
    const int*   bidx   = (const int*)  d_in[3];
    const float* RTs    = (const float*)d_in[4];
    const float* xibf   = (const float*)d_in[5];
    float*       out    = (float*)d_out;

    int BL = in_sizes[0];                       // B * L
    float* out_xyz = out + (size_t)BL * 144;

    int blocks = (BL + RPB - 1) / RPB;
    fused_kernel<<<blocks, 256, 0, stream>>>(seq, xyz, alphas, bidx, RTs, xibf,
                                             out, out_xyz, BL);
}

// Round 16
// 15.057 us; speedup vs baseline: 1.1487x; 1.1487x over previous
//
#include <hip/hip_runtime.h>

#define RPB 64              // residues per block (4 lanes per residue, 16 residues per wave)
#define FRS 16              // LDS floats per frame: full 4 rows, float4-aligned
#define RSS (9*FRS)         // 144 floats per residue (576B)

// ---------- helpers ----------

__device__ __forceinline__ float rsqz(float d) { return rsqrtf(fmaxf(d, 1e-24f)); }

__device__ __forceinline__ void angNorm(float x, float y, float& c, float& s) {
    float inv = rsqz(x*x + y*y);
    c = x * inv; s = y * inv;
}

// row-vector times 4x4 matrix; B points at 16 floats (row-major)
__device__ __forceinline__ float4 rowMat(const float4 f, const float* B) {
    float4 b0 = *reinterpret_cast<const float4*>(B);
    float4 b1 = *reinterpret_cast<const float4*>(B + 4);
    float4 b2 = *reinterpret_cast<const float4*>(B + 8);
    float4 b3 = *reinterpret_cast<const float4*>(B + 12);
    float4 o;
    o.x = f.x*b0.x + f.y*b1.x + f.z*b2.x + f.w*b3.x;
    o.y = f.x*b0.y + f.y*b1.y + f.z*b2.y + f.w*b3.y;
    o.z = f.x*b0.z + f.y*b1.z + f.z*b2.z + f.w*b3.z;
    o.w = f.x*b0.w + f.y*b1.w + f.z*b2.w + f.w*b3.w;
    return o;
}

__device__ __forceinline__ void rotXrow(float4& v, float c, float s) {
    float v1 = v.y, v2 = v.z;
    v.y = c*v1 + s*v2;
    v.z = c*v2 - s*v1;
}

__device__ __forceinline__ void rotZrow(float4& v, float c, float s) {
    float v0 = v.x, v1 = v.y;
    v.x = c*v0 + s*v1;
    v.y = c*v1 - s*v0;
}

__device__ __forceinline__ float4 applyG(const float4 f, const float G[3][3]) {
    float4 o;
    o.x = f.x*G[0][0] + f.y*G[1][0] + f.z*G[2][0];
    o.y = f.x*G[0][1] + f.y*G[1][1] + f.z*G[2][1];
    o.z = f.x*G[0][2] + f.y*G[1][2] + f.z*G[2][2];
    o.w = f.w;
    return o;
}

__device__ __forceinline__ void rotAxis3(float G[3][3], float c, float s,
                                         float u0, float u1, float u2) {
    float omc = 1.0f - c;
    G[0][0] = c + u0*u0*omc;    G[0][1] = u0*u1*omc - u2*s; G[0][2] = u0*u2*omc + u1*s;
    G[1][0] = u0*u1*omc + u2*s; G[1][1] = c + u1*u1*omc;    G[1][2] = u1*u2*omc - u0*s;
    G[2][0] = u0*u2*omc - u1*s; G[2][1] = u1*u2*omc + u0*s; G[2][2] = c + u2*u2*omc;
}

// ---------------------------- fused kernel ----------------------------
// 256 threads = 4 waves, fully independent (NO barriers). 4 lanes per
// residue; lane i carries row i of every frame (recurrence F_next=F_prev@M
// is row-decomposable). Frames go ONLY to LDS in the frame phase (float4
// rows); then a same-wave DENSE store phase writes out_fr as 9 fully
// contiguous 1KB bursts per wave (identical pattern to memset fills),
// eliminating the scattered 64B partial-line writes of earlier rounds.
// Atom phase: same wave, float4 LDS reads. Intra-wave lgkmcnt ordering
// guarantees produce->consume; no __syncthreads anywhere.

__global__ __launch_bounds__(256, 2) void fused_kernel(
    const int*   __restrict__ seq,     // (BL)
    const float* __restrict__ xyz,     // (BL,3,3)
    const float* __restrict__ alphas,  // (BL,10,2)
    const int*   __restrict__ bidx,    // (NAA,36)
    const float* __restrict__ RTs,     // (NAA,7,4,4)
    const float* __restrict__ xibf,    // (NAA,36,4)
    float*       __restrict__ out_fr,  // (BL,9,4,4)
    float*       __restrict__ out_xyz, // (BL,36,3)
    int BL)
{
    __shared__ __align__(16) float lds_fr[RPB * RSS];   // 36.9 KB
    __shared__ int lds_seq[RPB];

    const int tid   = threadIdx.x;
    const int lane  = tid & 63;
    const int wv    = tid >> 6;
    const int i     = lane & 3;             // row index 0..3
    const int res   = wv*16 + (lane >> 2);  // residue within block
    const int base  = blockIdx.x * RPB;
    const int t     = base + res;
    const bool valid = (t < BL);

    float* fl = lds_fr + res * RSS;

    if (valid) {
        int s = seq[t];
        if (i == 0) lds_seq[res] = s;
        const float* rb = RTs + (size_t)s * 112;
        const float* al = alphas + (size_t)t * 20;

        // ---- Gram-Schmidt (redundant across the 4 lanes) ----
        const float* p = xyz + (size_t)t * 9;
        float N0=p[0], N1=p[1], N2=p[2];
        float A0=p[3], A1=p[4], A2=p[5];
        float C0=p[6], C1=p[7], C2=p[8];
        float v10=C0-A0, v11=C1-A1, v12=C2-A2;
        float v20=N0-A0, v21=N1-A1, v22=N2-A2;
        float i1 = rsqz(v10*v10 + v11*v11 + v12*v12);
        float e10=v10*i1, e11=v11*i1, e12=v12*i1;
        float d  = e10*v20 + e11*v21 + e12*v22;
        float u20=v20-e10*d, u21=v21-e11*d, u22=v22-e12*d;
        float i2 = rsqz(u20*u20 + u21*u21 + u22*u22);
        float e20=u20*i2, e21=u21*i2, e22=u22*i2;
        float e30=e11*e22 - e12*e21;
        float e31=e12*e20 - e10*e22;
        float e32=e10*e21 - e11*e20;

        bool c0 = (i==0), c1 = (i==1), c2 = (i==2);
        float4 f0r;
        f0r.x = c0?e10 : c1?e11 : c2?e12 : 0.f;
        f0r.y = c0?e20 : c1?e21 : c2?e22 : 0.f;
        f0r.z = c0?e30 : c1?e31 : c2?e32 : 0.f;
        f0r.w = c0?A0  : c1?A1  : c2?A2  : 1.f;
        *reinterpret_cast<float4*>(fl + i*4) = f0r;

        // ---- angles ----
        const float4* a4p = reinterpret_cast<const float4*>(al);
        float4 q0 = a4p[0], q1 = a4p[1], q2 = a4p[2], q3 = a4p[3], q4 = a4p[4];
        float ca0,sa0, ca1,sa1, ca2,sa2, ca3,sa3, ca4,sa4;
        float ca5,sa5, ca6,sa6, ca7,sa7, ca8,sa8, ca9,sa9;
        angNorm(q0.x,q0.y, ca0,sa0);  angNorm(q0.z,q0.w, ca1,sa1);
        angNorm(q1.x,q1.y, ca2,sa2);  angNorm(q1.z,q1.w, ca3,sa3);
        angNorm(q2.x,q2.y, ca4,sa4);  angNorm(q2.z,q2.w, ca5,sa5);
        angNorm(q3.x,q3.y, ca6,sa6);  angNorm(q3.z,q3.w, ca7,sa7);
        angNorm(q4.x,q4.y, ca8,sa8);  angNorm(q4.z,q4.w, ca9,sa9);

        // ---- F1..F3 ----
        float4 rw;
        rw = rowMat(f0r, rb +  0); rotXrow(rw, ca0, sa0);
        *reinterpret_cast<float4*>(fl + 1*FRS + i*4) = rw;
        rw = rowMat(f0r, rb + 16); rotXrow(rw, ca1, sa1);
        *reinterpret_cast<float4*>(fl + 2*FRS + i*4) = rw;
        rw = rowMat(f0r, rb + 32); rotXrow(rw, ca2, sa2);
        *reinterpret_cast<float4*>(fl + 3*FRS + i*4) = rw;

        // ---- CB axes (redundant) ----
        const float* bxp = xibf + (size_t)s * 144;
        float4 b0 = reinterpret_cast<const float4*>(bxp)[0];
        float4 b1 = reinterpret_cast<const float4*>(bxp)[1];
        float4 b2 = reinterpret_cast<const float4*>(bxp)[2];
        float4 b4 = reinterpret_cast<const float4*>(bxp)[4];

        float NCr0 = 0.5f*(b2.x + b0.x), NCr1 = 0.5f*(b2.y + b0.y), NCr2 = 0.5f*(b2.z + b0.z);
        float ba0 = b4.x - b1.x, ba1 = b4.y - b1.y, ba2 = b4.z - b1.z;
        float w0 = NCr0 - b1.x, w1 = NCr1 - b1.y, w2 = NCr2 - b1.z;
        float x10 = ba1*w2 - ba2*w1, x11 = ba2*w0 - ba0*w2, x12 = ba0*w1 - ba1*w0;
        float in1 = rsqz(x10*x10 + x11*x11 + x12*x12);
        x10 *= in1; x11 *= in1; x12 *= in1;
        float NCp0 = b2.x - b0.x, NCp1 = b2.y - b0.y, NCp2 = b2.z - b0.z;
        float dp = NCp0*NCr0 + NCp1*NCr1 + NCp2*NCr2;
        float dr = NCr0*NCr0 + NCr1*NCr1 + NCr2*NCr2;
        float sf = dp / dr;
        float g0 = NCp0 - sf*NCr0, g1 = NCp1 - sf*NCr1, g2 = NCp2 - sf*NCr2;
        float x20 = ba1*g2 - ba2*g1, x21 = ba2*g0 - ba0*g2, x22 = ba0*g1 - ba1*g0;
        float in2 = rsqz(x20*x20 + x21*x21 + x22*x22);
        x20 *= in2; x21 *= in2; x22 *= in2;

        float G1[3][3], G2[3][3];
        rotAxis3(G1, ca7, sa7, x10, x11, x12);
        rotAxis3(G2, ca8, sa8, x20, x21, x22);

        // ---- F8 ----
        float4 f8r = applyG(applyG(f0r, G1), G2);
        *reinterpret_cast<float4*>(fl + 8*FRS + i*4) = f8r;

        // ---- F4..F7 suffix chain ----
        rw = rowMat(f8r, rb + 48); rotXrow(rw, ca3, sa3); rotZrow(rw, ca9, sa9);
        *reinterpret_cast<float4*>(fl + 4*FRS + i*4) = rw;
        rw = rowMat(rw, rb + 64); rotXrow(rw, ca4, sa4);
        *reinterpret_cast<float4*>(fl + 5*FRS + i*4) = rw;
        rw = rowMat(rw, rb + 80); rotXrow(rw, ca5, sa5);
        *reinterpret_cast<float4*>(fl + 6*FRS + i*4) = rw;
        rw = rowMat(rw, rb + 96); rotXrow(rw, ca6, sa6);
        *reinterpret_cast<float4*>(fl + 7*FRS + i*4) = rw;
    }

    const int wbase = wv * 16;

    // ---- dense frame store phase: 9 x 1KB contiguous bursts per wave ----
    // c = k*64 + lane indexes float4s across this wave's 16 residues:
    // out_fr float4 index = (base + wbase)*36 + c; LDS float4 index = wbase*36 + c.
#pragma unroll
    for (int k = 0; k < 9; ++k) {
        int c = k*64 + lane;                      // 0..575
        int tt = base + wbase + c/36;
        if (tt < BL) {
            float4 v = *reinterpret_cast<const float4*>(lds_fr + (wbase*36 + c)*4);
            *(reinterpret_cast<float4*>(out_fr) + (size_t)(base + wbase)*36 + c) = v;
        }
    }

    // ---- atom phase: same wave (no barriers), float4 LDS reads ----
#pragma unroll
    for (int k = 0; k < 9; ++k) {
        int c = k*64 + lane;              // 0..575 within this wave
        int lres = c / 36;
        int a = c - lres*36;
        int res2 = wbase + lres;
        int tt = base + res2;
        if (tt < BL) {
            int ss  = lds_seq[res2];
            int idx = bidx[ss*36 + a];
            float4 v = *reinterpret_cast<const float4*>(xibf + ((size_t)ss*36 + a)*4);
            const float* fp = lds_fr + res2*RSS + idx*FRS;
            float4 r0 = *reinterpret_cast<const float4*>(fp);
            float4 r1 = *reinterpret_cast<const float4*>(fp + 4);
            float4 r2 = *reinterpret_cast<const float4*>(fp + 8);
            size_t o = ((size_t)(base + wbase)*36 + c)*3;   // dense in c per wave
            out_xyz[o+0] = r0.x*v.x + r0.y*v.y + r0.z*v.z + r0.w*v.w;
            out_xyz[o+1] = r1.x*v.x + r1.y*v.y + r1.z*v.z + r1.w*v.w;
            out_xyz[o+2] = r2.x*v.x + r2.y*v.y + r2.z*v.z + r2.w*v.w;
        }
    }
}

// ---------------------------- launch ----------------------------

extern "C" void kernel_launch(void* const* d_in, const int* in_sizes, int n_in,
                              void* d_out, int out_size, void* d_ws, size_t ws_size,
                              hipStream_t stream) {
    const int*   seq    = (const int*)  d_in[0];
    const float* xyz    = (const float*)d_in[1];
    const float* alphas = (const float*)d_in[2];
    const int*   bidx   = (const int*)  d_in[3];
    const float* RTs    = (const float*)d_in[4];
    const float* xibf   = (const float*)d_in[5];
    float*       out    = (float*)d_out;

    int BL = in_sizes[0];                       // B * L
    float* out_xyz = out + (size_t)BL * 144;

    int blocks = (BL + RPB - 1) / RPB;
    fused_kernel<<<blocks, 256, 0, stream>>>(seq, xyz, alphas, bidx, RTs, xibf,
                                             out, out_xyz, BL);
}